// Round 9
// baseline (585.034 us; speedup 1.0000x reference)
//
#include <hip/hip_runtime.h>
#include <hip/hip_bf16.h>

#define N1 8192
#define N2 8192
#define CDIM 128
#define HC 60
#define WC 80
#define HIMG 480
#define WIMG 640
#define INV_DENOM (1.0f / (8192.0f * 256.0f))
#define CAP 2048              // per-row candidate capacity (mean ~1190, +16 sigma)
#define T0KEY 0xC140u         // monotone key of bf16(12.0)

using bf16x8 = __attribute__((ext_vector_type(8))) short;
using f32x4  = __attribute__((ext_vector_type(4))) float;

__device__ __forceinline__ ushort f2bf(float f) {
    union { float f; unsigned u; } x; x.f = f;
    unsigned u = x.u;
    unsigned r = (u + 0x7FFFu + ((u >> 16) & 1u)) >> 16;
    return (ushort)r;
}
__device__ __forceinline__ float bf2f(unsigned bits) {
    union { unsigned u; float f; } x; x.u = bits << 16; return x.f;
}
__device__ __forceinline__ unsigned bits2key(unsigned b) {   // u16 bf16 bits -> monotone key
    return b ^ ((b & 0x8000u) ? 0xFFFFu : 0x8000u);
}
__device__ __forceinline__ unsigned key2bits(unsigned k) {
    return k ^ ((k & 0x8000u) ? 0x8000u : 0xFFFFu);
}
__device__ __forceinline__ unsigned pair2key(unsigned x) {   // packed pair transform
    return x ^ 0x80008000u ^ (((x >> 15) & 0x00010001u) * 0x7FFFu);
}

// ---------- fp32 -> bf16 convert ----------
__global__ void cvt_kernel(const float* __restrict__ in, ushort* __restrict__ out, int n4) {
    int i = blockIdx.x * blockDim.x + threadIdx.x;
    if (i < n4) {
        float4 v = ((const float4*)in)[i];
        ushort4 o;
        o.x = f2bf(v.x); o.y = f2bf(v.y); o.z = f2bf(v.z); o.w = f2bf(v.w);
        ((ushort4*)out)[i] = o;
    }
}

// ---------- positive term ----------
__global__ void pos_kernel(const float* __restrict__ wkp1,
                           const float* __restrict__ kp1d,
                           const float* __restrict__ desc2,
                           float* __restrict__ out) {
    const int i = blockIdx.x;
    const int c = threadIdx.x;            // 128 threads = 2 waves
    float y = wkp1[2 * i], x = wkp1[2 * i + 1];
    float py = fminf(fmaxf(y / (float)(HIMG - 1) * (float)(HC - 1), 0.0f), (float)(HC - 1));
    float px = fminf(fmaxf(x / (float)(WIMG - 1) * (float)(WC - 1), 0.0f), (float)(WC - 1));
    int y0 = min(max((int)floorf(py), 0), HC - 2);
    int x0 = min(max((int)floorf(px), 0), WC - 2);
    float wy = py - (float)y0;
    float wx = px - (float)x0;
    const float* d = desc2 + (size_t)c * (HC * WC) + y0 * WC + x0;
    float v00 = d[0], v01 = d[1], v10 = d[WC], v11 = d[WC + 1];
    float v = v00 * (1.0f - wy) * (1.0f - wx) + v01 * (1.0f - wy) * wx
            + v10 * wy * (1.0f - wx) + v11 * wy * wx;
    float a = kp1d[(size_t)i * CDIM + c];
    float s2 = v * v, sav = a * v;
    #pragma unroll
    for (int off = 32; off >= 1; off >>= 1) {
        s2  += __shfl_down(s2, off);
        sav += __shfl_down(sav, off);
    }
    __shared__ float p2[2], pav[2];
    int wave = threadIdx.x >> 6, lane = threadIdx.x & 63;
    if (lane == 0) { p2[wave] = s2; pav[wave] = sav; }
    __syncthreads();
    if (threadIdx.x == 0) {
        float nrm = sqrtf(p2[0] + p2[1]);
        float pd = (pav[0] + pav[1]) / fmaxf(nrm, 1e-12f);
        float l = fmaxf(1.0f - pd, 0.0f) * (256.0f / 3.0f);
        atomicAdd(out, l * INV_DENOM);
    }
}

// ---------- masked GEMM -> candidate compaction (NO dots matrix) ----------
// Epilogue: value is a candidate iff its bf16 key > T0KEY (=12.0). Per 16-lane
// row-group: ballot submask -> leader does ONE atomicAdd(cnt[row], popc) (4
// active lanes/instr, distinct addresses), broadcast base via __shfl, each
// candidate lane stores its u16 bf16 bits. 134 MB dots write deleted.
__global__ __launch_bounds__(256, 2)
void gemm_kernel(const ushort* __restrict__ A, const ushort* __restrict__ B,
                 const float* __restrict__ wkp1, const float* __restrict__ kp2,
                 unsigned* __restrict__ cnt, ushort* __restrict__ cand) {
    const int n0 = blockIdx.x * 128;
    const int m0 = blockIdx.y * 128;
    const int lane = threadIdx.x & 63;
    const int wave = threadIdx.x >> 6;
    const int wm = wave >> 1, wn = wave & 1;
    const int lrow = lane & 15, quad = lane >> 4;

    f32x4 acc[4][4];
    #pragma unroll
    for (int i = 0; i < 4; i++)
        #pragma unroll
        for (int j = 0; j < 4; j++) acc[i][j] = (f32x4){0.f, 0.f, 0.f, 0.f};

    const int mbase = m0 + wm * 64 + lrow;
    const int nbase = n0 + wn * 64 + lrow;
    #pragma unroll
    for (int kit = 0; kit < 4; kit++) {
        const int kk = kit * 32 + quad * 8;
        bf16x8 af[4], bfr[4];
        #pragma unroll
        for (int t = 0; t < 4; t++) {
            af[t]  = *(const bf16x8*)(A + (size_t)(mbase + t * 16) * CDIM + kk);
            bfr[t] = *(const bf16x8*)(B + (size_t)(nbase + t * 16) * CDIM + kk);
        }
        #pragma unroll
        for (int mt = 0; mt < 4; mt++)
            #pragma unroll
            for (int nt = 0; nt < 4; nt++)
                acc[mt][nt] = __builtin_amdgcn_mfma_f32_16x16x32_bf16(
                    af[mt], bfr[nt], acc[mt][nt], 0, 0, 0);
    }

    // hoisted keypoint coords: 4 cols (this lane's j per nt), 16 rows (mt,r)
    float ky[4], kx[4];
    #pragma unroll
    for (int nt = 0; nt < 4; nt++) {
        int j = n0 + wn * 64 + nt * 16 + lrow;
        ky[nt] = kp2[2 * j]; kx[nt] = kp2[2 * j + 1];
    }
    float wyv[16], wxv[16];
    #pragma unroll
    for (int mt = 0; mt < 4; mt++)
        #pragma unroll
        for (int r = 0; r < 4; r++) {
            int i = m0 + wm * 64 + mt * 16 + quad * 4 + r;
            wyv[mt * 4 + r] = wkp1[2 * i]; wxv[mt * 4 + r] = wkp1[2 * i + 1];
        }

    const float thr = 2.0f * sqrtf(32.0f) + 0.1f;
    const float thr2 = thr * thr;
    #pragma unroll
    for (int nt = 0; nt < 4; nt++) {
        #pragma unroll
        for (int mt = 0; mt < 4; mt++) {
            #pragma unroll
            for (int r = 0; r < 4; r++) {
                const int i = m0 + wm * 64 + mt * 16 + quad * 4 + r;
                float dy = wyv[mt * 4 + r] - ky[nt];
                float dx = wxv[mt * 4 + r] - kx[nt];
                float v = acc[mt][nt][r];
                if (dy * dy + dx * dx <= thr2) v -= 5.0f;
                unsigned bits = f2bf(v);
                bool cd = bits2key(bits) > T0KEY;    // key-domain test == select's
                unsigned long long m = __ballot(cd);
                unsigned sub = (unsigned)(m >> (quad * 16)) & 0xFFFFu;
                int cq = (int)__popc(sub);
                int base = 0;
                if ((lane & 15) == 0 && cq > 0)
                    base = (int)atomicAdd(&cnt[i], (unsigned)cq);
                base = __shfl(base, lane & 48);      // quad-leader broadcast
                if (cd) {
                    int slot = base + (int)__popc(sub & ((1u << (lane & 15)) - 1u));
                    if (slot < CAP)
                        cand[(size_t)i * CAP + slot] = (ushort)bits;
                }
            }
        }
    }
}

// ---------- per-row top-256 hinge sum over candidates ----------
// One wave per row. Stage <=2048 keys in 4 KB LDS (wave-private, no barriers,
// stride-1 b128). 14-iter bisect over [T0KEY, 0xFFFF]; invariant cnt(>T0KEY)
// == cnt[row] >= 256 is CHECKED by construction (counter is exact). Exact
// closed-form tie handling as before. (c<256 or c>CAP are >16-sigma events;
// inputs are fixed-seed so behavior is deterministic.)
__global__ __launch_bounds__(256)
void select_kernel(const unsigned* __restrict__ cntbuf,
                   const ushort* __restrict__ cand,
                   float* __restrict__ out) {
    const int wave = threadIdx.x >> 6;
    const int lane = threadIdx.x & 63;
    const int row = blockIdx.x * 4 + wave;

    __shared__ uint4 keys[4][256];            // 2048 u16 keys per wave, 4 KB
    uint4* lk = keys[wave];

    const unsigned c = min(cntbuf[row], (unsigned)CAP);
    const ushort* crow = cand + (size_t)row * CAP;

    // stage: convert to monotone keys, zero out slots >= c (key 0 is inert:
    // every probed mid >= T0KEY > 0)
    #pragma unroll
    for (int j = 0; j < 4; j++) {
        int vi = lane + 64 * j;               // uint4 index (0..255)
        uint4 w = ((const uint4*)crow)[vi];
        unsigned g = (unsigned)vi * 8u;       // element index of w.x low half
        uint4 kq;
        unsigned kk;
        kk = pair2key(w.x);
        kq.x = ((g + 0 < c) ? (kk & 0xFFFFu) : 0u) | ((g + 1 < c) ? (kk & 0xFFFF0000u) : 0u);
        kk = pair2key(w.y);
        kq.y = ((g + 2 < c) ? (kk & 0xFFFFu) : 0u) | ((g + 3 < c) ? (kk & 0xFFFF0000u) : 0u);
        kk = pair2key(w.z);
        kq.z = ((g + 4 < c) ? (kk & 0xFFFFu) : 0u) | ((g + 5 < c) ? (kk & 0xFFFF0000u) : 0u);
        kk = pair2key(w.w);
        kq.w = ((g + 6 < c) ? (kk & 0xFFFFu) : 0u) | ((g + 7 < c) ? (kk & 0xFFFF0000u) : 0u);
        lk[vi] = kq;
    }

    int lo = (int)T0KEY, hi = 0xFFFF;         // cnt(>lo)=c>=256, cnt(>hi)=0
    #pragma unroll 1
    for (int it = 0; it < 14; it++) {         // range 16063 < 2^14
        unsigned midu = (unsigned)((lo + hi) >> 1);
        unsigned midhi = (midu << 16) | 0xFFFFu;
        int cn = 0;
        #pragma unroll
        for (int j = 0; j < 4; j++) {
            uint4 q = lk[lane + 64 * j];
            cn += (int)((q.x & 0xFFFFu) > midu) + (int)(q.x > midhi);
            cn += (int)((q.y & 0xFFFFu) > midu) + (int)(q.y > midhi);
            cn += (int)((q.z & 0xFFFFu) > midu) + (int)(q.z > midhi);
            cn += (int)((q.w & 0xFFFFu) > midu) + (int)(q.w > midhi);
        }
        #pragma unroll
        for (int off = 32; off >= 1; off >>= 1) cn += __shfl_down(cn, off);
        cn = __shfl(cn, 0);
        if (cn >= 256) lo = (int)midu; else hi = (int)midu;
    }
    const unsigned kt = (unsigned)hi;         // key of 256th-largest (attained)

    float s = 0.f; int cgt = 0;
    const unsigned kthi = (kt << 16) | 0xFFFFu;
    #pragma unroll
    for (int j = 0; j < 4; j++) {
        uint4 q = lk[lane + 64 * j];
        unsigned qs[4] = {q.x, q.y, q.z, q.w};
        #pragma unroll
        for (int u = 0; u < 4; u++) {
            unsigned lowk = qs[u] & 0xFFFFu, highk = qs[u] >> 16;
            if (lowk > kt)    { s += bf2f(key2bits(lowk))  - 0.2f; cgt++; }
            if (qs[u] > kthi) { s += bf2f(key2bits(highk)) - 0.2f; cgt++; }
        }
    }
    #pragma unroll
    for (int off = 32; off >= 1; off >>= 1) {
        s += __shfl_down(s, off);
        cgt += __shfl_down(cgt, off);
    }
    if (lane == 0) {
        float vt = bf2f(key2bits(kt));        // vt >= 12 > 0.2: hinges all positive
        float S = s + (float)(256 - cgt) * (vt - 0.2f);
        atomicAdd(out, S * INV_DENOM);
    }
}

extern "C" void kernel_launch(void* const* d_in, const int* in_sizes, int n_in,
                              void* d_out, int out_size, void* d_ws, size_t ws_size,
                              hipStream_t stream) {
    const float* wkp1  = (const float*)d_in[1];
    const float* kp2   = (const float*)d_in[2];
    const float* kp1d  = (const float*)d_in[3];
    const float* kp2d  = (const float*)d_in[4];
    const float* desc2 = (const float*)d_in[5];
    float* out = (float*)d_out;

    ushort* Abf = (ushort*)d_ws;                           // 2 MB
    ushort* Bbf = Abf + (size_t)N1 * CDIM;                 // 2 MB
    unsigned* cnt = (unsigned*)(Bbf + (size_t)N2 * CDIM);  // 32 KB
    ushort* cand = (ushort*)(cnt + N1);                    // 32 MB

    hipMemsetAsync(d_out, 0, sizeof(float), stream);
    hipMemsetAsync(cnt, 0, N1 * sizeof(unsigned), stream);

    int n4 = N1 * CDIM / 4;
    cvt_kernel<<<(n4 + 255) / 256, 256, 0, stream>>>(kp1d, Abf, n4);
    cvt_kernel<<<(n4 + 255) / 256, 256, 0, stream>>>(kp2d, Bbf, n4);

    pos_kernel<<<N1, 128, 0, stream>>>(wkp1, kp1d, desc2, out);

    dim3 grid(N2 / 128, N1 / 128);
    gemm_kernel<<<grid, 256, 0, stream>>>(Abf, Bbf, wkp1, kp2, cnt, cand);

    select_kernel<<<N1 / 4, 256, 0, stream>>>(cnt, cand, out);
}

// Round 10
// 263.111 us; speedup vs baseline: 2.2235x; 2.2235x over previous
//
#include <hip/hip_runtime.h>
#include <hip/hip_bf16.h>

#define N1 8192
#define N2 8192
#define CDIM 128
#define HC 60
#define WC 80
#define HIMG 480
#define WIMG 640
#define INV_DENOM (1.0f / (8192.0f * 256.0f))
#define T0KEY  0xC100u      // monotone key of bf16(8.0)
#define THIKEY 0xC200u      // monotone key of bf16(32.0)

using bf16x8 = __attribute__((ext_vector_type(8))) short;
using f32x4  = __attribute__((ext_vector_type(4))) float;

__device__ __forceinline__ ushort f2bf(float f) {
    union { float f; unsigned u; } x; x.f = f;
    unsigned u = x.u;
    unsigned r = (u + 0x7FFFu + ((u >> 16) & 1u)) >> 16;
    return (ushort)r;
}
__device__ __forceinline__ float bf2f(unsigned bits) {
    union { unsigned u; float f; } x; x.u = bits << 16; return x.f;
}
__device__ __forceinline__ unsigned key2bits(unsigned k) {
    return k ^ ((k & 0x8000u) ? 0x8000u : 0xFFFFu);
}
__device__ __forceinline__ unsigned pair2key(unsigned x) {   // packed pair transform
    return x ^ 0x80008000u ^ (((x >> 15) & 0x00010001u) * 0x7FFFu);
}

// ---------- fp32 -> bf16 convert ----------
__global__ void cvt_kernel(const float* __restrict__ in, ushort* __restrict__ out, int n4) {
    int i = blockIdx.x * blockDim.x + threadIdx.x;
    if (i < n4) {
        float4 v = ((const float4*)in)[i];
        ushort4 o;
        o.x = f2bf(v.x); o.y = f2bf(v.y); o.z = f2bf(v.z); o.w = f2bf(v.w);
        ((ushort4*)out)[i] = o;
    }
}

// ---------- positive term (plain store, no atomics) ----------
__global__ void pos_kernel(const float* __restrict__ wkp1,
                           const float* __restrict__ kp1d,
                           const float* __restrict__ desc2,
                           float* __restrict__ ploss) {
    const int i = blockIdx.x;
    const int c = threadIdx.x;            // 128 threads = 2 waves
    float y = wkp1[2 * i], x = wkp1[2 * i + 1];
    float py = fminf(fmaxf(y / (float)(HIMG - 1) * (float)(HC - 1), 0.0f), (float)(HC - 1));
    float px = fminf(fmaxf(x / (float)(WIMG - 1) * (float)(WC - 1), 0.0f), (float)(WC - 1));
    int y0 = min(max((int)floorf(py), 0), HC - 2);
    int x0 = min(max((int)floorf(px), 0), WC - 2);
    float wy = py - (float)y0;
    float wx = px - (float)x0;
    const float* d = desc2 + (size_t)c * (HC * WC) + y0 * WC + x0;
    float v00 = d[0], v01 = d[1], v10 = d[WC], v11 = d[WC + 1];
    float v = v00 * (1.0f - wy) * (1.0f - wx) + v01 * (1.0f - wy) * wx
            + v10 * wy * (1.0f - wx) + v11 * wy * wx;
    float a = kp1d[(size_t)i * CDIM + c];
    float s2 = v * v, sav = a * v;
    #pragma unroll
    for (int off = 32; off >= 1; off >>= 1) {
        s2  += __shfl_down(s2, off);
        sav += __shfl_down(sav, off);
    }
    __shared__ float p2[2], pav[2];
    int wave = threadIdx.x >> 6, lane = threadIdx.x & 63;
    if (lane == 0) { p2[wave] = s2; pav[wave] = sav; }
    __syncthreads();
    if (threadIdx.x == 0) {
        float nrm = sqrtf(p2[0] + p2[1]);
        float pd = (pav[0] + pav[1]) / fmaxf(nrm, 1e-12f);
        float l = fmaxf(1.0f - pd, 0.0f) * (256.0f / 3.0f);
        ploss[i] = l * INV_DENOM;
    }
}

// ---------- masked GEMM -> bf16 dots (R8's proven version) ----------
__global__ __launch_bounds__(256, 2)
void gemm_kernel(const ushort* __restrict__ A, const ushort* __restrict__ B,
                 const float* __restrict__ wkp1, const float* __restrict__ kp2,
                 ushort* __restrict__ dots, int m_off) {
    const int n0 = blockIdx.x * 128;
    const int m0 = m_off + blockIdx.y * 128;
    const int lane = threadIdx.x & 63;
    const int wave = threadIdx.x >> 6;
    const int wm = wave >> 1, wn = wave & 1;
    const int lrow = lane & 15, quad = lane >> 4;

    f32x4 acc[4][4];
    #pragma unroll
    for (int i = 0; i < 4; i++)
        #pragma unroll
        for (int j = 0; j < 4; j++) acc[i][j] = (f32x4){0.f, 0.f, 0.f, 0.f};

    const int mbase = m0 + wm * 64 + lrow;
    const int nbase = n0 + wn * 64 + lrow;
    #pragma unroll
    for (int kit = 0; kit < 4; kit++) {
        const int kk = kit * 32 + quad * 8;
        bf16x8 af[4], bfr[4];
        #pragma unroll
        for (int t = 0; t < 4; t++) {
            af[t]  = *(const bf16x8*)(A + (size_t)(mbase + t * 16) * CDIM + kk);
            bfr[t] = *(const bf16x8*)(B + (size_t)(nbase + t * 16) * CDIM + kk);
        }
        #pragma unroll
        for (int mt = 0; mt < 4; mt++)
            #pragma unroll
            for (int nt = 0; nt < 4; nt++)
                acc[mt][nt] = __builtin_amdgcn_mfma_f32_16x16x32_bf16(
                    af[mt], bfr[nt], acc[mt][nt], 0, 0, 0);
    }

    const float thr = 2.0f * sqrtf(32.0f) + 0.1f;
    const float thr2 = thr * thr;
    #pragma unroll
    for (int nt = 0; nt < 4; nt++) {
        int j = n0 + wn * 64 + nt * 16 + lrow;       // C/D: col = lane&15
        float ky = kp2[2 * j], kx = kp2[2 * j + 1];
        #pragma unroll
        for (int mt = 0; mt < 4; mt++) {
            #pragma unroll
            for (int r = 0; r < 4; r++) {
                int i = m0 + wm * 64 + mt * 16 + quad * 4 + r;  // row = (lane>>4)*4 + reg
                float wy = wkp1[2 * i], wx = wkp1[2 * i + 1];
                float dy = wy - ky, dx = wx - kx;
                float v = acc[mt][nt][r];
                if (dy * dy + dx * dx <= thr2) v -= 5.0f;
                dots[(size_t)(i - m_off) * N2 + j] = f2bf(v);
            }
        }
    }
}

// ---------- per-row top-256 hinge sum ----------
// Block per row. ONE full-row pass: each wave compacts key-pairs with either
// half > T0 into its PRIVATE LDS segment (ballot+mbcnt, 16-step chain, zero
// atomics). Bracket invariants (halves>T0 >= 256, halves>THI <= 255, segment
// fit) are CHECKED; violation -> raw restage + full-range bisect (exact
// always). Then ~8-iter bisect over ~1.7KB/wave, 1 barrier/iter. Result is a
// plain store to rloss[row] -- no same-address atomics anywhere.
__global__ __launch_bounds__(256)
void select_kernel(const ushort* __restrict__ dots, float* __restrict__ rloss,
                   int m_off) {
    const int row = blockIdx.x;
    const int wave = threadIdx.x >> 6;
    const int lane = threadIdx.x & 63;

    __shared__ unsigned buf[4][1024];     // 16 KB: candidate segs / raw restage
    __shared__ int s_icnt[2][4];
    __shared__ int s_lo[4], s_hi[4], s_len[4];
    __shared__ float s_sf[4];
    __shared__ int s_cg[4];

    const uint4* rp4 = (const uint4*)(dots + (size_t)row * N2);  // 1024 uint4
    unsigned* seg = buf[wave];

    // ---- pass 1: compact candidate pairs into private segment
    int base = 0;        // u32 slots allocated (wave-uniform)
    int cLow = 0, cHi = 0;   // per-lane HALF counts (>T0, >THI)
    const unsigned T0HI = (T0KEY << 16) | 0xFFFFu;
    const unsigned THIHI = (THIKEY << 16) | 0xFFFFu;
    #pragma unroll
    for (int j = 0; j < 4; j++) {
        uint4 w = rp4[wave * 256 + lane + 64 * j];
        unsigned xs[4] = {w.x, w.y, w.z, w.w};
        #pragma unroll
        for (int u = 0; u < 4; u++) {
            unsigned kk = pair2key(xs[u]);
            unsigned lowk = kk & 0xFFFFu;
            bool ql = lowk > T0KEY, qh = kk > T0HI;
            cLow += (int)ql + (int)qh;
            cHi  += (int)(lowk > THIKEY) + (int)(kk > THIHI);
            bool cd = ql || qh;
            unsigned long long m = __ballot(cd);
            int pre = __builtin_amdgcn_mbcnt_hi((unsigned)(m >> 32),
                      __builtin_amdgcn_mbcnt_lo((unsigned)m, 0u));
            int slot = base + pre;
            if (cd && slot < 1024) seg[slot] = kk;
            base += (int)__popcll(m);
        }
    }
    #pragma unroll
    for (int off = 32; off >= 1; off >>= 1) {
        cLow += __shfl_down(cLow, off);
        cHi  += __shfl_down(cHi, off);
    }
    if (lane == 0) {
        s_lo[wave] = cLow; s_hi[wave] = cHi; s_len[wave] = base;
    }
    __syncthreads();

    const int totLow = s_lo[0] + s_lo[1] + s_lo[2] + s_lo[3];
    const int totHi  = s_hi[0] + s_hi[1] + s_hi[2] + s_hi[3];
    const bool fit = (s_len[0] <= 1024) & (s_len[1] <= 1024)
                   & (s_len[2] <= 1024) & (s_len[3] <= 1024);
    const bool ok = (totLow >= 256) && (totHi <= 255) && fit;

    int lo, hi, myLen;
    if (ok) {
        lo = (int)T0KEY; hi = (int)THIKEY;
        myLen = s_len[wave];
    } else {
        // raw restage of this wave's quarter (exact fallback)
        #pragma unroll
        for (int j = 0; j < 4; j++) {
            uint4 w = rp4[wave * 256 + lane + 64 * j];
            uint4 kq;
            kq.x = pair2key(w.x); kq.y = pair2key(w.y);
            kq.z = pair2key(w.z); kq.w = pair2key(w.w);
            ((uint4*)seg)[lane + 64 * j] = kq;
        }
        lo = -1; hi = 65535;
        myLen = 1024;
    }
    // zero-pad to uint4-per-lane granularity (key 0 inert: all mids >= 0)
    const int mw = (myLen + 255) >> 8;     // uint4-iters per lane
    for (int p = myLen + lane; p < mw * 256; p += 64)
        if (p < 1024) seg[p] = 0u;

    // ---- bisect; invariant: cnt(>lo) >= 256, cnt(>hi) <= 255
    int it = 0;
    while (hi - lo > 1) {
        unsigned midu = (unsigned)((lo + hi) >> 1);
        unsigned midhi = (midu << 16) | 0xFFFFu;
        int c = 0;
        for (int j = 0; j < mw; j++) {
            uint4 q = ((const uint4*)seg)[lane + 64 * j];
            c += (int)((q.x & 0xFFFFu) > midu) + (int)(q.x > midhi);
            c += (int)((q.y & 0xFFFFu) > midu) + (int)(q.y > midhi);
            c += (int)((q.z & 0xFFFFu) > midu) + (int)(q.z > midhi);
            c += (int)((q.w & 0xFFFFu) > midu) + (int)(q.w > midhi);
        }
        #pragma unroll
        for (int off = 32; off >= 1; off >>= 1) c += __shfl_down(c, off);
        if (lane == 0) s_icnt[it & 1][wave] = c;
        __syncthreads();
        int total = s_icnt[it & 1][0] + s_icnt[it & 1][1]
                  + s_icnt[it & 1][2] + s_icnt[it & 1][3];
        if (total >= 256) lo = (int)midu; else hi = (int)midu;
        it++;
    }
    const unsigned kt = (unsigned)hi;      // key of 256th-largest (attained)

    // ---- epilogue: exact closed form under ties
    float s = 0.f; int cgt = 0;
    const unsigned kthi = (kt << 16) | 0xFFFFu;
    for (int j = 0; j < mw; j++) {
        uint4 q = ((const uint4*)seg)[lane + 64 * j];
        unsigned qs[4] = {q.x, q.y, q.z, q.w};
        #pragma unroll
        for (int u = 0; u < 4; u++) {
            unsigned lowk = qs[u] & 0xFFFFu, highk = qs[u] >> 16;
            if (lowk > kt)    { s += fmaxf(bf2f(key2bits(lowk))  - 0.2f, 0.0f); cgt++; }
            if (qs[u] > kthi) { s += fmaxf(bf2f(key2bits(highk)) - 0.2f, 0.0f); cgt++; }
        }
    }
    #pragma unroll
    for (int off = 32; off >= 1; off >>= 1) {
        s += __shfl_down(s, off);
        cgt += __shfl_down(cgt, off);
    }
    if (lane == 0) { s_sf[wave] = s; s_cg[wave] = cgt; }
    __syncthreads();
    if (threadIdx.x == 0) {
        float st = s_sf[0] + s_sf[1] + s_sf[2] + s_sf[3];
        int ct = s_cg[0] + s_cg[1] + s_cg[2] + s_cg[3];
        float vt = bf2f(key2bits(kt));
        float S = st + (float)(256 - ct) * fmaxf(vt - 0.2f, 0.0f);
        rloss[m_off + row] = S * INV_DENOM;
    }
}

// ---------- final reduce: sum 2*N1 floats -> out[0] ----------
__global__ void reduce_kernel(const float* __restrict__ a, float* __restrict__ out) {
    const int t = threadIdx.x;
    float s = 0.f;
    for (int i = t; i < 2 * N1; i += 256) s += a[i];
    #pragma unroll
    for (int off = 32; off >= 1; off >>= 1) s += __shfl_down(s, off);
    __shared__ float ws[4];
    int wave = t >> 6, lane = t & 63;
    if (lane == 0) ws[wave] = s;
    __syncthreads();
    if (t == 0) out[0] = ws[0] + ws[1] + ws[2] + ws[3];
}

extern "C" void kernel_launch(void* const* d_in, const int* in_sizes, int n_in,
                              void* d_out, int out_size, void* d_ws, size_t ws_size,
                              hipStream_t stream) {
    const float* wkp1  = (const float*)d_in[1];
    const float* kp2   = (const float*)d_in[2];
    const float* kp1d  = (const float*)d_in[3];
    const float* kp2d  = (const float*)d_in[4];
    const float* desc2 = (const float*)d_in[5];
    float* out = (float*)d_out;

    ushort* Abf  = (ushort*)d_ws;                          // 2 MB
    ushort* Bbf  = Abf + (size_t)N1 * CDIM;                // 2 MB
    float*  loss = (float*)(Bbf + (size_t)N2 * CDIM);      // 2*N1 floats (pos then rows)
    ushort* dots = (ushort*)(loss + 2 * N1);               // chunked dots

    size_t head_bytes = (size_t)(N1 + N2) * CDIM * sizeof(ushort) + 2 * N1 * sizeof(float);
    size_t avail = (ws_size > head_bytes) ? (ws_size - head_bytes) : 0;
    long rows_chunk = (long)(avail / ((size_t)N2 * sizeof(ushort)));
    rows_chunk = (rows_chunk / 128) * 128;
    if (rows_chunk > N1) rows_chunk = N1;
    if (rows_chunk < 128) rows_chunk = 128;      // requires ws >= ~6 MB

    int n4 = N1 * CDIM / 4;
    cvt_kernel<<<(n4 + 255) / 256, 256, 0, stream>>>(kp1d, Abf, n4);
    cvt_kernel<<<(n4 + 255) / 256, 256, 0, stream>>>(kp2d, Bbf, n4);

    pos_kernel<<<N1, 128, 0, stream>>>(wkp1, kp1d, desc2, loss);

    for (int r0 = 0; r0 < N1; r0 += (int)rows_chunk) {
        int rows = (int)((N1 - r0 < rows_chunk) ? (N1 - r0) : rows_chunk);
        dim3 grid(N2 / 128, rows / 128);
        gemm_kernel<<<grid, 256, 0, stream>>>(Abf, Bbf, wkp1, kp2, dots, r0);
        select_kernel<<<rows, 256, 0, stream>>>(dots, loss + N1, r0);
    }

    reduce_kernel<<<1, 256, 0, stream>>>(loss, out);
}

// Round 11
// 241.413 us; speedup vs baseline: 2.4234x; 1.0899x over previous
//
#include <hip/hip_runtime.h>
#include <hip/hip_bf16.h>

#define N1 8192
#define N2 8192
#define CDIM 128
#define HC 60
#define WC 80
#define HIMG 480
#define WIMG 640
#define INV_DENOM (1.0f / (8192.0f * 256.0f))
#define T0KEY  0xC100u      // monotone key of bf16(8.0)
#define THIKEY 0xC200u      // monotone key of bf16(32.0)

using bf16x8 = __attribute__((ext_vector_type(8))) short;
using f32x4  = __attribute__((ext_vector_type(4))) float;

__device__ __forceinline__ ushort f2bf(float f) {
    union { float f; unsigned u; } x; x.f = f;
    unsigned u = x.u;
    unsigned r = (u + 0x7FFFu + ((u >> 16) & 1u)) >> 16;
    return (ushort)r;
}
__device__ __forceinline__ float bf2f(unsigned bits) {
    union { unsigned u; float f; } x; x.u = bits << 16; return x.f;
}
__device__ __forceinline__ unsigned key2bits(unsigned k) {
    return k ^ ((k & 0x8000u) ? 0x8000u : 0xFFFFu);
}
__device__ __forceinline__ unsigned pair2key(unsigned x) {   // packed pair transform
    return x ^ 0x80008000u ^ (((x >> 15) & 0x00010001u) * 0x7FFFu);
}

// ---------- fp32 -> bf16 convert ----------
__global__ void cvt_kernel(const float* __restrict__ in, ushort* __restrict__ out, int n4) {
    int i = blockIdx.x * blockDim.x + threadIdx.x;
    if (i < n4) {
        float4 v = ((const float4*)in)[i];
        ushort4 o;
        o.x = f2bf(v.x); o.y = f2bf(v.y); o.z = f2bf(v.z); o.w = f2bf(v.w);
        ((ushort4*)out)[i] = o;
    }
}

// ---------- positive term (plain store, no atomics) ----------
__global__ void pos_kernel(const float* __restrict__ wkp1,
                           const float* __restrict__ kp1d,
                           const float* __restrict__ desc2,
                           float* __restrict__ ploss) {
    const int i = blockIdx.x;
    const int c = threadIdx.x;            // 128 threads = 2 waves
    float y = wkp1[2 * i], x = wkp1[2 * i + 1];
    float py = fminf(fmaxf(y / (float)(HIMG - 1) * (float)(HC - 1), 0.0f), (float)(HC - 1));
    float px = fminf(fmaxf(x / (float)(WIMG - 1) * (float)(WC - 1), 0.0f), (float)(WC - 1));
    int y0 = min(max((int)floorf(py), 0), HC - 2);
    int x0 = min(max((int)floorf(px), 0), WC - 2);
    float wy = py - (float)y0;
    float wx = px - (float)x0;
    const float* d = desc2 + (size_t)c * (HC * WC) + y0 * WC + x0;
    float v00 = d[0], v01 = d[1], v10 = d[WC], v11 = d[WC + 1];
    float v = v00 * (1.0f - wy) * (1.0f - wx) + v01 * (1.0f - wy) * wx
            + v10 * wy * (1.0f - wx) + v11 * wy * wx;
    float a = kp1d[(size_t)i * CDIM + c];
    float s2 = v * v, sav = a * v;
    #pragma unroll
    for (int off = 32; off >= 1; off >>= 1) {
        s2  += __shfl_down(s2, off);
        sav += __shfl_down(sav, off);
    }
    __shared__ float p2[2], pav[2];
    int wave = threadIdx.x >> 6, lane = threadIdx.x & 63;
    if (lane == 0) { p2[wave] = s2; pav[wave] = sav; }
    __syncthreads();
    if (threadIdx.x == 0) {
        float nrm = sqrtf(p2[0] + p2[1]);
        float pd = (pav[0] + pav[1]) / fmaxf(nrm, 1e-12f);
        float l = fmaxf(1.0f - pd, 0.0f) * (256.0f / 3.0f);
        ploss[i] = l * INV_DENOM;
    }
}

// ---------- masked GEMM -> bf16 dots, PACKED PERMUTED stores ----------
// Select is column-order-invariant, so each lane packs its 4 same-row values
// (nt=0..3, TRUE cols j=n0+wn*64+nt*16+lrow used for the mask) into one u64
// stored at permuted position n0+wn*64+lrow*4. Each 16-lane quad writes 128
// contiguous bytes -> full-cacheline writeback (R10's 165MB-for-134MB partial
// -line amplification gone), 16 dwordx2 stores/thread vs 64 shorts.
__global__ __launch_bounds__(256, 2)
void gemm_kernel(const ushort* __restrict__ A, const ushort* __restrict__ B,
                 const float* __restrict__ wkp1, const float* __restrict__ kp2,
                 ushort* __restrict__ dots, int m_off) {
    const int n0 = blockIdx.x * 128;
    const int m0 = m_off + blockIdx.y * 128;
    const int lane = threadIdx.x & 63;
    const int wave = threadIdx.x >> 6;
    const int wm = wave >> 1, wn = wave & 1;
    const int lrow = lane & 15, quad = lane >> 4;

    f32x4 acc[4][4];
    #pragma unroll
    for (int i = 0; i < 4; i++)
        #pragma unroll
        for (int j = 0; j < 4; j++) acc[i][j] = (f32x4){0.f, 0.f, 0.f, 0.f};

    const int mbase = m0 + wm * 64 + lrow;
    const int nbase = n0 + wn * 64 + lrow;
    #pragma unroll
    for (int kit = 0; kit < 4; kit++) {
        const int kk = kit * 32 + quad * 8;
        bf16x8 af[4], bfr[4];
        #pragma unroll
        for (int t = 0; t < 4; t++) {
            af[t]  = *(const bf16x8*)(A + (size_t)(mbase + t * 16) * CDIM + kk);
            bfr[t] = *(const bf16x8*)(B + (size_t)(nbase + t * 16) * CDIM + kk);
        }
        #pragma unroll
        for (int mt = 0; mt < 4; mt++)
            #pragma unroll
            for (int nt = 0; nt < 4; nt++)
                acc[mt][nt] = __builtin_amdgcn_mfma_f32_16x16x32_bf16(
                    af[mt], bfr[nt], acc[mt][nt], 0, 0, 0);
    }

    // true columns for the mask (per nt), this lane
    float ky[4], kx[4];
    #pragma unroll
    for (int nt = 0; nt < 4; nt++) {
        int j = n0 + wn * 64 + nt * 16 + lrow;
        ky[nt] = kp2[2 * j]; kx[nt] = kp2[2 * j + 1];
    }

    const float thr = 2.0f * sqrtf(32.0f) + 0.1f;
    const float thr2 = thr * thr;
    const size_t colbase = (size_t)(n0 + wn * 64 + lrow * 4);
    #pragma unroll
    for (int mt = 0; mt < 4; mt++) {
        #pragma unroll
        for (int r = 0; r < 4; r++) {
            const int i = m0 + wm * 64 + mt * 16 + quad * 4 + r;  // row
            const float wy = wkp1[2 * i], wx = wkp1[2 * i + 1];
            unsigned h[4];
            #pragma unroll
            for (int nt = 0; nt < 4; nt++) {
                float dy = wy - ky[nt], dx = wx - kx[nt];
                float v = acc[mt][nt][r];
                if (dy * dy + dx * dx <= thr2) v -= 5.0f;
                h[nt] = (unsigned)f2bf(v);
            }
            unsigned long long pk = (unsigned long long)(h[0] | (h[1] << 16))
                                  | ((unsigned long long)(h[2] | (h[3] << 16)) << 32);
            *(unsigned long long*)(dots + (size_t)(i - m_off) * N2 + colbase) = pk;
        }
    }
}

// ---------- per-row top-256 hinge sum (unchanged from R10) ----------
// Block per row. ONE full-row pass: each wave compacts key-pairs with either
// half > T0 into its PRIVATE LDS segment (ballot+mbcnt, zero atomics).
// Bracket invariants CHECKED; violation -> raw restage + full-range bisect
// (exact always). ~8-iter bisect, 1 barrier/iter. Plain store to rloss[row].
__global__ __launch_bounds__(256)
void select_kernel(const ushort* __restrict__ dots, float* __restrict__ rloss,
                   int m_off) {
    const int row = blockIdx.x;
    const int wave = threadIdx.x >> 6;
    const int lane = threadIdx.x & 63;

    __shared__ unsigned buf[4][1024];     // 16 KB: candidate segs / raw restage
    __shared__ int s_icnt[2][4];
    __shared__ int s_lo[4], s_hi[4], s_len[4];
    __shared__ float s_sf[4];
    __shared__ int s_cg[4];

    const uint4* rp4 = (const uint4*)(dots + (size_t)row * N2);  // 1024 uint4
    unsigned* seg = buf[wave];

    // ---- pass 1: compact candidate pairs into private segment
    int base = 0;        // u32 slots allocated (wave-uniform)
    int cLow = 0, cHi = 0;   // per-lane HALF counts (>T0, >THI)
    const unsigned T0HI = (T0KEY << 16) | 0xFFFFu;
    const unsigned THIHI = (THIKEY << 16) | 0xFFFFu;
    #pragma unroll
    for (int j = 0; j < 4; j++) {
        uint4 w = rp4[wave * 256 + lane + 64 * j];
        unsigned xs[4] = {w.x, w.y, w.z, w.w};
        #pragma unroll
        for (int u = 0; u < 4; u++) {
            unsigned kk = pair2key(xs[u]);
            unsigned lowk = kk & 0xFFFFu;
            bool ql = lowk > T0KEY, qh = kk > T0HI;
            cLow += (int)ql + (int)qh;
            cHi  += (int)(lowk > THIKEY) + (int)(kk > THIHI);
            bool cd = ql || qh;
            unsigned long long m = __ballot(cd);
            int pre = __builtin_amdgcn_mbcnt_hi((unsigned)(m >> 32),
                      __builtin_amdgcn_mbcnt_lo((unsigned)m, 0u));
            int slot = base + pre;
            if (cd && slot < 1024) seg[slot] = kk;
            base += (int)__popcll(m);
        }
    }
    #pragma unroll
    for (int off = 32; off >= 1; off >>= 1) {
        cLow += __shfl_down(cLow, off);
        cHi  += __shfl_down(cHi, off);
    }
    if (lane == 0) {
        s_lo[wave] = cLow; s_hi[wave] = cHi; s_len[wave] = base;
    }
    __syncthreads();

    const int totLow = s_lo[0] + s_lo[1] + s_lo[2] + s_lo[3];
    const int totHi  = s_hi[0] + s_hi[1] + s_hi[2] + s_hi[3];
    const bool fit = (s_len[0] <= 1024) & (s_len[1] <= 1024)
                   & (s_len[2] <= 1024) & (s_len[3] <= 1024);
    const bool ok = (totLow >= 256) && (totHi <= 255) && fit;

    int lo, hi, myLen;
    if (ok) {
        lo = (int)T0KEY; hi = (int)THIKEY;
        myLen = s_len[wave];
    } else {
        // raw restage of this wave's quarter (exact fallback)
        #pragma unroll
        for (int j = 0; j < 4; j++) {
            uint4 w = rp4[wave * 256 + lane + 64 * j];
            uint4 kq;
            kq.x = pair2key(w.x); kq.y = pair2key(w.y);
            kq.z = pair2key(w.z); kq.w = pair2key(w.w);
            ((uint4*)seg)[lane + 64 * j] = kq;
        }
        lo = -1; hi = 65535;
        myLen = 1024;
    }
    // zero-pad to uint4-per-lane granularity (key 0 inert: all mids >= 0)
    const int mw = (myLen + 255) >> 8;     // uint4-iters per lane
    for (int p = myLen + lane; p < mw * 256; p += 64)
        if (p < 1024) seg[p] = 0u;

    // ---- bisect; invariant: cnt(>lo) >= 256, cnt(>hi) <= 255
    int it = 0;
    while (hi - lo > 1) {
        unsigned midu = (unsigned)((lo + hi) >> 1);
        unsigned midhi = (midu << 16) | 0xFFFFu;
        int c = 0;
        for (int j = 0; j < mw; j++) {
            uint4 q = ((const uint4*)seg)[lane + 64 * j];
            c += (int)((q.x & 0xFFFFu) > midu) + (int)(q.x > midhi);
            c += (int)((q.y & 0xFFFFu) > midu) + (int)(q.y > midhi);
            c += (int)((q.z & 0xFFFFu) > midu) + (int)(q.z > midhi);
            c += (int)((q.w & 0xFFFFu) > midu) + (int)(q.w > midhi);
        }
        #pragma unroll
        for (int off = 32; off >= 1; off >>= 1) c += __shfl_down(c, off);
        if (lane == 0) s_icnt[it & 1][wave] = c;
        __syncthreads();
        int total = s_icnt[it & 1][0] + s_icnt[it & 1][1]
                  + s_icnt[it & 1][2] + s_icnt[it & 1][3];
        if (total >= 256) lo = (int)midu; else hi = (int)midu;
        it++;
    }
    const unsigned kt = (unsigned)hi;      // key of 256th-largest (attained)

    // ---- epilogue: exact closed form under ties
    float s = 0.f; int cgt = 0;
    const unsigned kthi = (kt << 16) | 0xFFFFu;
    for (int j = 0; j < mw; j++) {
        uint4 q = ((const uint4*)seg)[lane + 64 * j];
        unsigned qs[4] = {q.x, q.y, q.z, q.w};
        #pragma unroll
        for (int u = 0; u < 4; u++) {
            unsigned lowk = qs[u] & 0xFFFFu, highk = qs[u] >> 16;
            if (lowk > kt)    { s += fmaxf(bf2f(key2bits(lowk))  - 0.2f, 0.0f); cgt++; }
            if (qs[u] > kthi) { s += fmaxf(bf2f(key2bits(highk)) - 0.2f, 0.0f); cgt++; }
        }
    }
    #pragma unroll
    for (int off = 32; off >= 1; off >>= 1) {
        s += __shfl_down(s, off);
        cgt += __shfl_down(cgt, off);
    }
    if (lane == 0) { s_sf[wave] = s; s_cg[wave] = cgt; }
    __syncthreads();
    if (threadIdx.x == 0) {
        float st = s_sf[0] + s_sf[1] + s_sf[2] + s_sf[3];
        int ct = s_cg[0] + s_cg[1] + s_cg[2] + s_cg[3];
        float vt = bf2f(key2bits(kt));
        float S = st + (float)(256 - ct) * fmaxf(vt - 0.2f, 0.0f);
        rloss[m_off + row] = S * INV_DENOM;
    }
}

// ---------- final reduce: sum 2*N1 floats -> out[0] ----------
__global__ void reduce_kernel(const float* __restrict__ a, float* __restrict__ out) {
    const int t = threadIdx.x;
    float s = 0.f;
    for (int i = t; i < 2 * N1; i += 256) s += a[i];
    #pragma unroll
    for (int off = 32; off >= 1; off >>= 1) s += __shfl_down(s, off);
    __shared__ float ws[4];
    int wave = t >> 6, lane = t & 63;
    if (lane == 0) ws[wave] = s;
    __syncthreads();
    if (t == 0) out[0] = ws[0] + ws[1] + ws[2] + ws[3];
}

extern "C" void kernel_launch(void* const* d_in, const int* in_sizes, int n_in,
                              void* d_out, int out_size, void* d_ws, size_t ws_size,
                              hipStream_t stream) {
    const float* wkp1  = (const float*)d_in[1];
    const float* kp2   = (const float*)d_in[2];
    const float* kp1d  = (const float*)d_in[3];
    const float* kp2d  = (const float*)d_in[4];
    const float* desc2 = (const float*)d_in[5];
    float* out = (float*)d_out;

    ushort* Abf  = (ushort*)d_ws;                          // 2 MB
    ushort* Bbf  = Abf + (size_t)N1 * CDIM;                // 2 MB
    float*  loss = (float*)(Bbf + (size_t)N2 * CDIM);      // 2*N1 floats (pos then rows)
    ushort* dots = (ushort*)(loss + 2 * N1);               // chunked dots

    size_t head_bytes = (size_t)(N1 + N2) * CDIM * sizeof(ushort) + 2 * N1 * sizeof(float);
    size_t avail = (ws_size > head_bytes) ? (ws_size - head_bytes) : 0;
    long rows_chunk = (long)(avail / ((size_t)N2 * sizeof(ushort)));
    rows_chunk = (rows_chunk / 128) * 128;
    if (rows_chunk > N1) rows_chunk = N1;
    if (rows_chunk < 128) rows_chunk = 128;      // requires ws >= ~6 MB

    int n4 = N1 * CDIM / 4;
    cvt_kernel<<<(n4 + 255) / 256, 256, 0, stream>>>(kp1d, Abf, n4);
    cvt_kernel<<<(n4 + 255) / 256, 256, 0, stream>>>(kp2d, Bbf, n4);

    pos_kernel<<<N1, 128, 0, stream>>>(wkp1, kp1d, desc2, loss);

    for (int r0 = 0; r0 < N1; r0 += (int)rows_chunk) {
        int rows = (int)((N1 - r0 < rows_chunk) ? (N1 - r0) : rows_chunk);
        dim3 grid(N2 / 128, rows / 128);
        gemm_kernel<<<grid, 256, 0, stream>>>(Abf, Bbf, wkp1, kp2, dots, r0);
        select_kernel<<<rows, 256, 0, stream>>>(dots, loss + N1, r0);
    }

    reduce_kernel<<<1, 256, 0, stream>>>(loss, out);
}

// Round 12
// 238.752 us; speedup vs baseline: 2.4504x; 1.0111x over previous
//
#include <hip/hip_runtime.h>
#include <hip/hip_bf16.h>

#define N1 8192
#define N2 8192
#define CDIM 128
#define HC 60
#define WC 80
#define HIMG 480
#define WIMG 640
#define NPIX (HC * WC)
#define INV_DENOM (1.0f / (8192.0f * 256.0f))
#define T0KEY  0xC100u      // monotone key of bf16(8.0)
#define THIKEY 0xC200u      // monotone key of bf16(32.0)

using bf16x8 = __attribute__((ext_vector_type(8))) short;
using f32x4  = __attribute__((ext_vector_type(4))) float;

__device__ __forceinline__ ushort f2bf(float f) {
    union { float f; unsigned u; } x; x.f = f;
    unsigned u = x.u;
    unsigned r = (u + 0x7FFFu + ((u >> 16) & 1u)) >> 16;
    return (ushort)r;
}
__device__ __forceinline__ float bf2f(unsigned bits) {
    union { unsigned u; float f; } x; x.u = bits << 16; return x.f;
}
__device__ __forceinline__ unsigned key2bits(unsigned k) {
    return k ^ ((k & 0x8000u) ? 0x8000u : 0xFFFFu);
}
__device__ __forceinline__ unsigned pair2key(unsigned x) {   // packed pair transform
    return x ^ 0x80008000u ^ (((x >> 15) & 0x00010001u) * 0x7FFFu);
}

// ---------- fp32 -> bf16 convert ----------
__global__ void cvt_kernel(const float* __restrict__ in, ushort* __restrict__ out, int n4) {
    int i = blockIdx.x * blockDim.x + threadIdx.x;
    if (i < n4) {
        float4 v = ((const float4*)in)[i];
        ushort4 o;
        o.x = f2bf(v.x); o.y = f2bf(v.y); o.z = f2bf(v.z); o.w = f2bf(v.w);
        ((ushort4*)out)[i] = o;
    }
}

// ---------- desc2 transpose: [C][Hc*Wc] -> [Hc*Wc][C] ----------
// 2.4 MB one-time; makes pos_kernel's per-keypoint channel reads lane-contiguous.
__global__ void tr_kernel(const float* __restrict__ in, float* __restrict__ out) {
    int e = blockIdx.x * blockDim.x + threadIdx.x;   // 614400 elements
    if (e < NPIX * CDIM) {
        int c = e & (CDIM - 1);
        int p = e >> 7;
        out[e] = in[c * NPIX + p];
    }
}

// ---------- positive term (coalesced via desc2T, plain store) ----------
__global__ void pos_kernel(const float* __restrict__ wkp1,
                           const float* __restrict__ kp1d,
                           const float* __restrict__ desc2T,
                           float* __restrict__ ploss) {
    const int i = blockIdx.x;
    const int c = threadIdx.x;            // 128 threads = 2 waves
    float y = wkp1[2 * i], x = wkp1[2 * i + 1];
    float py = fminf(fmaxf(y / (float)(HIMG - 1) * (float)(HC - 1), 0.0f), (float)(HC - 1));
    float px = fminf(fmaxf(x / (float)(WIMG - 1) * (float)(WC - 1), 0.0f), (float)(WC - 1));
    int y0 = min(max((int)floorf(py), 0), HC - 2);
    int x0 = min(max((int)floorf(px), 0), WC - 2);
    float wy = py - (float)y0;
    float wx = px - (float)x0;
    const int p00 = y0 * WC + x0;
    float v00 = desc2T[(size_t)p00 * CDIM + c];
    float v01 = desc2T[(size_t)(p00 + 1) * CDIM + c];
    float v10 = desc2T[(size_t)(p00 + WC) * CDIM + c];
    float v11 = desc2T[(size_t)(p00 + WC + 1) * CDIM + c];
    float v = v00 * (1.0f - wy) * (1.0f - wx) + v01 * (1.0f - wy) * wx
            + v10 * wy * (1.0f - wx) + v11 * wy * wx;
    float a = kp1d[(size_t)i * CDIM + c];
    float s2 = v * v, sav = a * v;
    #pragma unroll
    for (int off = 32; off >= 1; off >>= 1) {
        s2  += __shfl_down(s2, off);
        sav += __shfl_down(sav, off);
    }
    __shared__ float p2[2], pav[2];
    int wave = threadIdx.x >> 6, lane = threadIdx.x & 63;
    if (lane == 0) { p2[wave] = s2; pav[wave] = sav; }
    __syncthreads();
    if (threadIdx.x == 0) {
        float nrm = sqrtf(p2[0] + p2[1]);
        float pd = (pav[0] + pav[1]) / fmaxf(nrm, 1e-12f);
        float l = fmaxf(1.0f - pd, 0.0f) * (256.0f / 3.0f);
        ploss[i] = l * INV_DENOM;
    }
}

// ---------- masked GEMM -> bf16 dots, packed permuted stores ----------
// R11 post-mortem: launch_bounds(256,2) self-capped occupancy at 28% on a
// latency-bound kernel. Now (256,4) -> 4 blocks/CU, and the keypoint coords
// are staged in LDS (2 KB, coalesced) so the epilogue does broadcast ds_reads
// instead of 20 scattered 8B L2 loads per thread.
__global__ __launch_bounds__(256, 4)
void gemm_kernel(const ushort* __restrict__ A, const ushort* __restrict__ B,
                 const float* __restrict__ wkp1, const float* __restrict__ kp2,
                 ushort* __restrict__ dots, int m_off) {
    const int n0 = blockIdx.x * 128;
    const int m0 = m_off + blockIdx.y * 128;
    const int lane = threadIdx.x & 63;
    const int wave = threadIdx.x >> 6;
    const int wm = wave >> 1, wn = wave & 1;
    const int lrow = lane & 15, quad = lane >> 4;

    __shared__ float s_w[256];    // wkp1[m0..m0+128) pairs
    __shared__ float s_k[256];    // kp2 [n0..n0+128) pairs
    s_w[threadIdx.x] = wkp1[2 * m0 + threadIdx.x];
    s_k[threadIdx.x] = kp2[2 * n0 + threadIdx.x];
    __syncthreads();

    f32x4 acc[4][4];
    #pragma unroll
    for (int i = 0; i < 4; i++)
        #pragma unroll
        for (int j = 0; j < 4; j++) acc[i][j] = (f32x4){0.f, 0.f, 0.f, 0.f};

    const int mbase = m0 + wm * 64 + lrow;
    const int nbase = n0 + wn * 64 + lrow;
    #pragma unroll
    for (int kit = 0; kit < 4; kit++) {
        const int kk = kit * 32 + quad * 8;
        bf16x8 af[4], bfr[4];
        #pragma unroll
        for (int t = 0; t < 4; t++) {
            af[t]  = *(const bf16x8*)(A + (size_t)(mbase + t * 16) * CDIM + kk);
            bfr[t] = *(const bf16x8*)(B + (size_t)(nbase + t * 16) * CDIM + kk);
        }
        #pragma unroll
        for (int mt = 0; mt < 4; mt++)
            #pragma unroll
            for (int nt = 0; nt < 4; nt++)
                acc[mt][nt] = __builtin_amdgcn_mfma_f32_16x16x32_bf16(
                    af[mt], bfr[nt], acc[mt][nt], 0, 0, 0);
    }

    // true columns for the mask (per nt), this lane — from LDS
    float ky[4], kx[4];
    #pragma unroll
    for (int nt = 0; nt < 4; nt++) {
        int jl = wn * 64 + nt * 16 + lrow;
        ky[nt] = s_k[2 * jl]; kx[nt] = s_k[2 * jl + 1];
    }

    const float thr = 2.0f * sqrtf(32.0f) + 0.1f;
    const float thr2 = thr * thr;
    const size_t colbase = (size_t)(n0 + wn * 64 + lrow * 4);
    #pragma unroll
    for (int mt = 0; mt < 4; mt++) {
        #pragma unroll
        for (int r = 0; r < 4; r++) {
            const int il = wm * 64 + mt * 16 + quad * 4 + r;      // local row
            const int i = m0 + il;
            const float wy = s_w[2 * il], wx = s_w[2 * il + 1];   // broadcast LDS
            unsigned h[4];
            #pragma unroll
            for (int nt = 0; nt < 4; nt++) {
                float dy = wy - ky[nt], dx = wx - kx[nt];
                float v = acc[mt][nt][r];
                if (dy * dy + dx * dx <= thr2) v -= 5.0f;
                h[nt] = (unsigned)f2bf(v);
            }
            unsigned long long pk = (unsigned long long)(h[0] | (h[1] << 16))
                                  | ((unsigned long long)(h[2] | (h[3] << 16)) << 32);
            *(unsigned long long*)(dots + (size_t)(i - m_off) * N2 + colbase) = pk;
        }
    }
}

// ---------- per-row top-256 hinge sum (unchanged from R10/R11) ----------
__global__ __launch_bounds__(256)
void select_kernel(const ushort* __restrict__ dots, float* __restrict__ rloss,
                   int m_off) {
    const int row = blockIdx.x;
    const int wave = threadIdx.x >> 6;
    const int lane = threadIdx.x & 63;

    __shared__ unsigned buf[4][1024];     // 16 KB: candidate segs / raw restage
    __shared__ int s_icnt[2][4];
    __shared__ int s_lo[4], s_hi[4], s_len[4];
    __shared__ float s_sf[4];
    __shared__ int s_cg[4];

    const uint4* rp4 = (const uint4*)(dots + (size_t)row * N2);  // 1024 uint4
    unsigned* seg = buf[wave];

    // ---- pass 1: compact candidate pairs into private segment
    int base = 0;        // u32 slots allocated (wave-uniform)
    int cLow = 0, cHi = 0;   // per-lane HALF counts (>T0, >THI)
    const unsigned T0HI = (T0KEY << 16) | 0xFFFFu;
    const unsigned THIHI = (THIKEY << 16) | 0xFFFFu;
    #pragma unroll
    for (int j = 0; j < 4; j++) {
        uint4 w = rp4[wave * 256 + lane + 64 * j];
        unsigned xs[4] = {w.x, w.y, w.z, w.w};
        #pragma unroll
        for (int u = 0; u < 4; u++) {
            unsigned kk = pair2key(xs[u]);
            unsigned lowk = kk & 0xFFFFu;
            bool ql = lowk > T0KEY, qh = kk > T0HI;
            cLow += (int)ql + (int)qh;
            cHi  += (int)(lowk > THIKEY) + (int)(kk > THIHI);
            bool cd = ql || qh;
            unsigned long long m = __ballot(cd);
            int pre = __builtin_amdgcn_mbcnt_hi((unsigned)(m >> 32),
                      __builtin_amdgcn_mbcnt_lo((unsigned)m, 0u));
            int slot = base + pre;
            if (cd && slot < 1024) seg[slot] = kk;
            base += (int)__popcll(m);
        }
    }
    #pragma unroll
    for (int off = 32; off >= 1; off >>= 1) {
        cLow += __shfl_down(cLow, off);
        cHi  += __shfl_down(cHi, off);
    }
    if (lane == 0) {
        s_lo[wave] = cLow; s_hi[wave] = cHi; s_len[wave] = base;
    }
    __syncthreads();

    const int totLow = s_lo[0] + s_lo[1] + s_lo[2] + s_lo[3];
    const int totHi  = s_hi[0] + s_hi[1] + s_hi[2] + s_hi[3];
    const bool fit = (s_len[0] <= 1024) & (s_len[1] <= 1024)
                   & (s_len[2] <= 1024) & (s_len[3] <= 1024);
    const bool ok = (totLow >= 256) && (totHi <= 255) && fit;

    int lo, hi, myLen;
    if (ok) {
        lo = (int)T0KEY; hi = (int)THIKEY;
        myLen = s_len[wave];
    } else {
        // raw restage of this wave's quarter (exact fallback)
        #pragma unroll
        for (int j = 0; j < 4; j++) {
            uint4 w = rp4[wave * 256 + lane + 64 * j];
            uint4 kq;
            kq.x = pair2key(w.x); kq.y = pair2key(w.y);
            kq.z = pair2key(w.z); kq.w = pair2key(w.w);
            ((uint4*)seg)[lane + 64 * j] = kq;
        }
        lo = -1; hi = 65535;
        myLen = 1024;
    }
    // zero-pad to uint4-per-lane granularity (key 0 inert: all mids >= 0)
    const int mw = (myLen + 255) >> 8;     // uint4-iters per lane
    for (int p = myLen + lane; p < mw * 256; p += 64)
        if (p < 1024) seg[p] = 0u;

    // ---- bisect; invariant: cnt(>lo) >= 256, cnt(>hi) <= 255
    int it = 0;
    while (hi - lo > 1) {
        unsigned midu = (unsigned)((lo + hi) >> 1);
        unsigned midhi = (midu << 16) | 0xFFFFu;
        int c = 0;
        for (int j = 0; j < mw; j++) {
            uint4 q = ((const uint4*)seg)[lane + 64 * j];
            c += (int)((q.x & 0xFFFFu) > midu) + (int)(q.x > midhi);
            c += (int)((q.y & 0xFFFFu) > midu) + (int)(q.y > midhi);
            c += (int)((q.z & 0xFFFFu) > midu) + (int)(q.z > midhi);
            c += (int)((q.w & 0xFFFFu) > midu) + (int)(q.w > midhi);
        }
        #pragma unroll
        for (int off = 32; off >= 1; off >>= 1) c += __shfl_down(c, off);
        if (lane == 0) s_icnt[it & 1][wave] = c;
        __syncthreads();
        int total = s_icnt[it & 1][0] + s_icnt[it & 1][1]
                  + s_icnt[it & 1][2] + s_icnt[it & 1][3];
        if (total >= 256) lo = (int)midu; else hi = (int)midu;
        it++;
    }
    const unsigned kt = (unsigned)hi;      // key of 256th-largest (attained)

    // ---- epilogue: exact closed form under ties
    float s = 0.f; int cgt = 0;
    const unsigned kthi = (kt << 16) | 0xFFFFu;
    for (int j = 0; j < mw; j++) {
        uint4 q = ((const uint4*)seg)[lane + 64 * j];
        unsigned qs[4] = {q.x, q.y, q.z, q.w};
        #pragma unroll
        for (int u = 0; u < 4; u++) {
            unsigned lowk = qs[u] & 0xFFFFu, highk = qs[u] >> 16;
            if (lowk > kt)    { s += fmaxf(bf2f(key2bits(lowk))  - 0.2f, 0.0f); cgt++; }
            if (qs[u] > kthi) { s += fmaxf(bf2f(key2bits(highk)) - 0.2f, 0.0f); cgt++; }
        }
    }
    #pragma unroll
    for (int off = 32; off >= 1; off >>= 1) {
        s += __shfl_down(s, off);
        cgt += __shfl_down(cgt, off);
    }
    if (lane == 0) { s_sf[wave] = s; s_cg[wave] = cgt; }
    __syncthreads();
    if (threadIdx.x == 0) {
        float st = s_sf[0] + s_sf[1] + s_sf[2] + s_sf[3];
        int ct = s_cg[0] + s_cg[1] + s_cg[2] + s_cg[3];
        float vt = bf2f(key2bits(kt));
        float S = st + (float)(256 - ct) * fmaxf(vt - 0.2f, 0.0f);
        rloss[m_off + row] = S * INV_DENOM;
    }
}

// ---------- final reduce: sum 2*N1 floats -> out[0] ----------
__global__ void reduce_kernel(const float* __restrict__ a, float* __restrict__ out) {
    const int t = threadIdx.x;
    float s = 0.f;
    for (int i = t; i < 2 * N1; i += 256) s += a[i];
    #pragma unroll
    for (int off = 32; off >= 1; off >>= 1) s += __shfl_down(s, off);
    __shared__ float ws[4];
    int wave = t >> 6, lane = t & 63;
    if (lane == 0) ws[wave] = s;
    __syncthreads();
    if (t == 0) out[0] = ws[0] + ws[1] + ws[2] + ws[3];
}

extern "C" void kernel_launch(void* const* d_in, const int* in_sizes, int n_in,
                              void* d_out, int out_size, void* d_ws, size_t ws_size,
                              hipStream_t stream) {
    const float* wkp1  = (const float*)d_in[1];
    const float* kp2   = (const float*)d_in[2];
    const float* kp1d  = (const float*)d_in[3];
    const float* kp2d  = (const float*)d_in[4];
    const float* desc2 = (const float*)d_in[5];
    float* out = (float*)d_out;

    ushort* Abf   = (ushort*)d_ws;                         // 2 MB
    ushort* Bbf   = Abf + (size_t)N1 * CDIM;               // 2 MB
    float*  loss  = (float*)(Bbf + (size_t)N2 * CDIM);     // 64 KB (pos then rows)
    float*  d2T   = loss + 2 * N1;                         // 2.4 MB transposed desc2
    ushort* dots  = (ushort*)(d2T + (size_t)NPIX * CDIM);  // chunked dots

    size_t head_bytes = (size_t)(N1 + N2) * CDIM * sizeof(ushort)
                      + 2 * N1 * sizeof(float)
                      + (size_t)NPIX * CDIM * sizeof(float);
    size_t avail = (ws_size > head_bytes) ? (ws_size - head_bytes) : 0;
    long rows_chunk = (long)(avail / ((size_t)N2 * sizeof(ushort)));
    rows_chunk = (rows_chunk / 128) * 128;
    if (rows_chunk > N1) rows_chunk = N1;
    if (rows_chunk < 128) rows_chunk = 128;      // requires ws >= ~9 MB

    int n4 = N1 * CDIM / 4;
    cvt_kernel<<<(n4 + 255) / 256, 256, 0, stream>>>(kp1d, Abf, n4);
    cvt_kernel<<<(n4 + 255) / 256, 256, 0, stream>>>(kp2d, Bbf, n4);
    tr_kernel<<<(NPIX * CDIM + 255) / 256, 256, 0, stream>>>(desc2, d2T);

    pos_kernel<<<N1, 128, 0, stream>>>(wkp1, kp1d, d2T, loss);

    for (int r0 = 0; r0 < N1; r0 += (int)rows_chunk) {
        int rows = (int)((N1 - r0 < rows_chunk) ? (N1 - r0) : rows_chunk);
        dim3 grid(N2 / 128, rows / 128);
        gemm_kernel<<<grid, 256, 0, stream>>>(Abf, Bbf, wkp1, kp2, dots, r0);
        select_kernel<<<rows, 256, 0, stream>>>(dots, loss + N1, r0);
    }

    reduce_kernel<<<1, 256, 0, stream>>>(loss, out);
}